// Round 6
// baseline (184.441 us; speedup 1.0000x reference)
//
#include <hip/hip_runtime.h>
#include <hip/hip_bf16.h>

// Segment-mean gather (AGGR_MEAN graph pooling).
//   input [N=100000, C=128] f32; idxn [E] int; seg_ids [E] int (sorted);
//   degs [N_OUT=50000] int; out [N_OUT, C] f32.
//
// R5/R6: L2-miss path (~3 TB/s random-granule) is the bottleneck; make
// gathers L2-RESIDENT. Repack bf16 table into 8 channel-chunks
// tab[chunk][node][8xu32] (3.2 MB/chunk < 4 MiB per-XCD L2), pin chunk c to
// XCD c via blockIdx%8. idxn read nontemporally; out stored nt (via clang
// ext_vector — HIP float2 is rejected by the builtin). starts[] precomputed.

typedef float fvec2 __attribute__((ext_vector_type(2)));

static __device__ inline uint16_t f2bf_rne(float f) {
  uint32_t u = __float_as_uint(f);
  return (uint16_t)((u + 0x7fffu + ((u >> 16) & 1u)) >> 16);
}

// ---- pass 1: f32 [N][128] -> bf16-packed blocked [8][N][8 u32] ------------
__global__ __launch_bounds__(256) void cvt_blocked_kernel(
    const float* __restrict__ in, uint32_t* __restrict__ tab, int n_nodes) {
  const int total = n_nodes * 64;  // one u32 (2 channels) per element
  const float2* __restrict__ in2 = (const float2*)in;
  int i = blockIdx.x * blockDim.x + threadIdx.x;
  const int stride = gridDim.x * blockDim.x;
  for (; i < total; i += stride) {
    const int node = i >> 6;
    const int chp64 = i & 63;          // which u32 of the row (0..63)
    const int chunk = chp64 >> 3;      // 8 chunks of 16 channels
    const int within = chp64 & 7;      // u32 within chunk
    float2 v = in2[i];                 // channels 2*chp64, 2*chp64+1
    uint32_t p = (uint32_t)f2bf_rne(v.x) | ((uint32_t)f2bf_rne(v.y) << 16);
    tab[((size_t)chunk * n_nodes + node) * 8 + within] = p;
  }
}

// ---- pass 2: starts[s] = lower_bound(seg_ids, s) --------------------------
__global__ __launch_bounds__(256) void starts_kernel(
    const int* __restrict__ seg_ids, int* __restrict__ starts, int n_out,
    int E) {
  const int s = blockIdx.x * blockDim.x + threadIdx.x;
  if (s >= n_out) return;
  int lo = 0, hi = E;
  while (lo < hi) {
    int mid = (lo + hi) >> 1;
    if (seg_ids[mid] < s) lo = mid + 1; else hi = mid;
  }
  starts[s] = lo;
}

// ---- pass 3: gather+mean, chunk c pinned to XCD c -------------------------
// block = 256 (4 waves); chunk = bid & 7 (== XCD on round-robin mapping);
// wave w handles segment (bid>>3)*4 + w for channels [chunk*16, chunk*16+16).
// lane: e_sub = (t&63)>>3 (edge slot), chp = t&7 (u32 within 32B row-slice).
__global__ __launch_bounds__(256) void seg_mean_chunk_kernel(
    const uint32_t* __restrict__ tab,
    const int* __restrict__ idxn,
    const int* __restrict__ starts,
    const int* __restrict__ degs,
    float* __restrict__ out,
    int n_out, int n_nodes) {
  const int bid = blockIdx.x;
  const int chunk = bid & 7;
  const int wave = threadIdx.x >> 6;
  const int s = (bid >> 3) * 4 + wave;
  if (s >= n_out) return;

  const int t = threadIdx.x & 63;
  const int e_sub = t >> 3;  // 0..7
  const int chp = t & 7;     // 0..7

  const int deg = degs[s];
  const int start = starts[s];

  const uint32_t* __restrict__ slice = tab + (size_t)chunk * n_nodes * 8;

  float ax = 0.f, ay = 0.f;

  if (deg > 0) {
    const int dm1 = deg - 1;
    for (int e0 = 0; e0 < deg; e0 += 32) {  // 32 edges/iter (4 per lane)
      int idx[4];
#pragma unroll
      for (int k = 0; k < 4; ++k) {
        int ei = e0 + 8 * k + e_sub;
        ei = ei < dm1 ? ei : dm1;
        idx[k] = __builtin_nontemporal_load(idxn + start + ei);
      }
      uint32_t v[4];
#pragma unroll
      for (int k = 0; k < 4; ++k)
        v[k] = slice[(size_t)idx[k] * 8 + chp];
#pragma unroll
      for (int k = 0; k < 4; ++k) {
        const float w = (e0 + 8 * k + e_sub < deg) ? 1.0f : 0.0f;
        ax += __uint_as_float(v[k] << 16) * w;
        ay += __uint_as_float(v[k] & 0xffff0000u) * w;
      }
    }
  }

  // reduce across the 8 edge-slots (lane bits 3,4,5)
  ax += __shfl_xor(ax, 8, 64);
  ay += __shfl_xor(ay, 8, 64);
  ax += __shfl_xor(ax, 16, 64);
  ay += __shfl_xor(ay, 16, 64);
  ax += __shfl_xor(ax, 32, 64);
  ay += __shfl_xor(ay, 32, 64);

  if (e_sub == 0) {
    const float inv = (deg > 0) ? (1.0f / (float)deg) : 0.0f;
    fvec2 r;
    r.x = ax * inv;
    r.y = ay * inv;
    // channels [chunk*16 + 2*chp, +1] of segment s; 8 lanes -> 64B contiguous
    fvec2* dst = (fvec2*)(out + (size_t)s * 128 + chunk * 16) + chp;
    __builtin_nontemporal_store(r, dst);
  }
}

// ---- fallback (ws too small): R4 flat bf16 path ---------------------------
__global__ __launch_bounds__(256) void cvt_bf16_kernel(
    const float* __restrict__ in, uint32_t* __restrict__ tab, int npairs2) {
  const float4* __restrict__ in4 = (const float4*)in;
  uint2* __restrict__ o2 = (uint2*)tab;
  int i = blockIdx.x * blockDim.x + threadIdx.x;
  const int stride = gridDim.x * blockDim.x;
  for (; i < npairs2; i += stride) {
    float4 v = in4[i];
    uint2 r;
    r.x = (uint32_t)f2bf_rne(v.x) | ((uint32_t)f2bf_rne(v.y) << 16);
    r.y = (uint32_t)f2bf_rne(v.z) | ((uint32_t)f2bf_rne(v.w) << 16);
    o2[i] = r;
  }
}

__global__ __launch_bounds__(64) void seg_mean_bf16_kernel(
    const uint32_t* __restrict__ tab,
    const int* __restrict__ idxn,
    const int* __restrict__ seg_ids,
    const int* __restrict__ degs,
    float* __restrict__ out,
    int n_out, int E) {
  const int s = blockIdx.x;
  if (s >= n_out) return;
  const int deg = degs[s];
  const int t = threadIdx.x;
  int lo = 0, hi = E;
  while (lo < hi) {
    int mid = (lo + hi) >> 1;
    if (seg_ids[mid] < s) lo = mid + 1; else hi = mid;
  }
  const int start = lo;
  float accx = 0.f, accy = 0.f;
  if (deg > 0) {
    const int dm1 = deg - 1;
    constexpr int U = 16;
    int nidx[U];
#pragma unroll
    for (int k = 0; k < U; ++k) {
      int ei = k < dm1 ? k : dm1;
      nidx[k] = idxn[start + ei];
    }
    for (int e = 0; e < deg; e += U) {
      int cur[U];
#pragma unroll
      for (int k = 0; k < U; ++k) cur[k] = nidx[k];
      const int en = e + U;
      if (en < deg) {
#pragma unroll
        for (int k = 0; k < U; ++k) {
          int ei = en + k;
          ei = ei < dm1 ? ei : dm1;
          nidx[k] = idxn[start + ei];
        }
      }
      uint32_t v[U];
#pragma unroll
      for (int k = 0; k < U; ++k)
        v[k] = tab[(size_t)((uint32_t)cur[k] * 64u + (uint32_t)t)];
      if (en <= deg) {
#pragma unroll
        for (int k = 0; k < U; ++k) {
          accx += __uint_as_float(v[k] << 16);
          accy += __uint_as_float(v[k] & 0xffff0000u);
        }
      } else {
#pragma unroll
        for (int k = 0; k < U; ++k) {
          const float w = (e + k < deg) ? 1.0f : 0.0f;
          accx += __uint_as_float(v[k] << 16) * w;
          accy += __uint_as_float(v[k] & 0xffff0000u) * w;
        }
      }
    }
  }
  const float inv = (deg > 0) ? (1.0f / (float)deg) : 0.0f;
  float2 r;
  r.x = accx * inv;
  r.y = accy * inv;
  ((float2*)out)[(size_t)s * 64 + t] = r;
}

extern "C" void kernel_launch(void* const* d_in, const int* in_sizes, int n_in,
                              void* d_out, int out_size, void* d_ws, size_t ws_size,
                              hipStream_t stream) {
  const float* input  = (const float*)d_in[0];
  const int* idxn     = (const int*)d_in[1];
  const int* seg_ids  = (const int*)d_in[2];
  const int* degs     = (const int*)d_in[3];
  float* out          = (float*)d_out;

  const int n_elem  = in_sizes[0];        // N * C
  const int E       = in_sizes[1];
  const int n_out   = in_sizes[3];
  const int n_nodes = n_elem / 128;       // C = 128

  const size_t tab_bytes    = (size_t)n_elem * 2;
  const size_t starts_bytes = (size_t)n_out * 4;

  if (ws_size >= tab_bytes + starts_bytes + 256) {
    uint32_t* tab = (uint32_t*)d_ws;
    size_t starts_off = (tab_bytes + 255) & ~(size_t)255;
    int* starts = (int*)((char*)d_ws + starts_off);

    cvt_blocked_kernel<<<2048, 256, 0, stream>>>(input, tab, n_nodes);
    starts_kernel<<<(n_out + 255) / 256, 256, 0, stream>>>(seg_ids, starts,
                                                           n_out, E);
    const int segs_per_blk = 4;
    const int grid = 8 * ((n_out + segs_per_blk - 1) / segs_per_blk);
    seg_mean_chunk_kernel<<<grid, 256, 0, stream>>>(tab, idxn, starts, degs,
                                                    out, n_out, n_nodes);
  } else if (ws_size >= tab_bytes) {
    uint32_t* tab = (uint32_t*)d_ws;
    cvt_bf16_kernel<<<2048, 256, 0, stream>>>(input, tab, n_elem / 4);
    seg_mean_bf16_kernel<<<n_out, 64, 0, stream>>>(tab, idxn, seg_ids, degs,
                                                   out, n_out, E);
  }
}

// Round 7
// 79.913 us; speedup vs baseline: 2.3080x; 2.3080x over previous
//
#include <hip/hip_runtime.h>
#include <hip/hip_bf16.h>

// Segment-mean gather (AGGR_MEAN graph pooling).
//   input [N=100000, C=128] f32; idxn [E] int; seg_ids [E] int (sorted);
//   degs [N_OUT=50000] int; out [N_OUT, C] f32.
//
// R7: both R4 (flat, 1 edge per 256B VMEM) and R6 (chunked, 32B granules)
// plateau at ~80-85 G granule-requests/s -> the constraint is VMEM
// transaction rate / per-wave MLP, not HBM bytes (R6 cut FETCH 5x, got 2x
// slower). Fix: dwordx4 gathers (16B/lane, 16 lanes per 256B bf16 row) ->
// ONE instruction covers 4 edges; 8 instrs (32 edges) in flight per wave.
// Segment's edge indices loaded once (coalesced, deg<=63) and broadcast via
// __shfl to form gather addresses. 4 waves/block.

typedef float fvec4 __attribute__((ext_vector_type(4)));

static __device__ inline uint16_t f2bf_rne(float f) {
  uint32_t u = __float_as_uint(f);
  return (uint16_t)((u + 0x7fffu + ((u >> 16) & 1u)) >> 16);
}

// ---- pass 1: f32 [N][128] -> packed bf16 [N][64 u32] (flat) ---------------
__global__ __launch_bounds__(256) void cvt_bf16_kernel(
    const float* __restrict__ in, uint32_t* __restrict__ tab, int npairs2) {
  const float4* __restrict__ in4 = (const float4*)in;
  uint2* __restrict__ o2 = (uint2*)tab;
  int i = blockIdx.x * blockDim.x + threadIdx.x;
  const int stride = gridDim.x * blockDim.x;
  for (; i < npairs2; i += stride) {
    float4 v = in4[i];
    uint2 r;
    r.x = (uint32_t)f2bf_rne(v.x) | ((uint32_t)f2bf_rne(v.y) << 16);
    r.y = (uint32_t)f2bf_rne(v.z) | ((uint32_t)f2bf_rne(v.w) << 16);
    o2[i] = r;
  }
}

// ---- pass 2: starts[s] = lower_bound(seg_ids, s) --------------------------
__global__ __launch_bounds__(256) void starts_kernel(
    const int* __restrict__ seg_ids, int* __restrict__ starts, int n_out,
    int E) {
  const int s = blockIdx.x * blockDim.x + threadIdx.x;
  if (s >= n_out) return;
  int lo = 0, hi = E;
  while (lo < hi) {
    int mid = (lo + hi) >> 1;
    if (seg_ids[mid] < s) lo = mid + 1; else hi = mid;
  }
  starts[s] = lo;
}

// ---- pass 3: gather+mean, 4 edges per VMEM instruction --------------------
// wave = 1 segment. lane: slot = t>>4 (edge slot 0..3), cw = t&15 (16B chunk
// of the 256B row = channels cw*8..cw*8+8). Per 32-edge iteration each lane
// issues 8 independent dwordx4 gathers (addresses from shfl-broadcast idx).
__global__ __launch_bounds__(256) void seg_mean_x4_kernel(
    const uint4* __restrict__ tab,   // [n_nodes][16] uint4 rows
    const int* __restrict__ idxn,
    const int* __restrict__ starts,
    const int* __restrict__ degs,
    float* __restrict__ out,
    int n_out) {
  const int wave = threadIdx.x >> 6;
  const int s = blockIdx.x * 4 + wave;
  if (s >= n_out) return;
  const int t = threadIdx.x & 63;
  const int slot = t >> 4;
  const int cw = t & 15;

  const int deg = degs[s];
  const int start = starts[s];

  float acc[8];
#pragma unroll
  for (int j = 0; j < 8; ++j) acc[j] = 0.f;

  for (int cb = 0; cb < deg; cb += 64) {   // deg<=63 -> single pass normally
    const int cl = min(deg - cb, 64);
    // one coalesced load covers this chunk's edge indices
    const int idx_t = idxn[start + cb + (t < cl ? t : cl - 1)];

    for (int e0 = 0; e0 < cl; e0 += 32) {
      uint4 v[8];
      int loc[8];
#pragma unroll
      for (int k = 0; k < 8; ++k) {
        loc[k] = e0 + 4 * k + slot;
        const int lc = min(loc[k], cl - 1);
        const int node = __shfl(idx_t, lc, 64);
        v[k] = tab[(size_t)node * 16 + cw];
      }
#pragma unroll
      for (int k = 0; k < 8; ++k) {
        const float w = (loc[k] < cl) ? 1.0f : 0.0f;
        const uint32_t* p = (const uint32_t*)&v[k];
#pragma unroll
        for (int j = 0; j < 4; ++j) {
          acc[2 * j]     += __uint_as_float(p[j] << 16) * w;
          acc[2 * j + 1] += __uint_as_float(p[j] & 0xffff0000u) * w;
        }
      }
    }
  }

  // reduce across the 4 edge slots (lane bits 4,5)
#pragma unroll
  for (int j = 0; j < 8; ++j) {
    acc[j] += __shfl_xor(acc[j], 16, 64);
    acc[j] += __shfl_xor(acc[j], 32, 64);
  }

  if (t < 16) {
    const float inv = (deg > 0) ? (1.0f / (float)deg) : 0.0f;
    fvec4 r0, r1;
    r0.x = acc[0] * inv; r0.y = acc[1] * inv;
    r0.z = acc[2] * inv; r0.w = acc[3] * inv;
    r1.x = acc[4] * inv; r1.y = acc[5] * inv;
    r1.z = acc[6] * inv; r1.w = acc[7] * inv;
    fvec4* dst = (fvec4*)(out + (size_t)s * 128 + t * 8);
    dst[0] = r0;
    dst[1] = r1;
  }
}

// ---- fallback (ws too small for starts): R4 flat bf16 path ----------------
__global__ __launch_bounds__(64) void seg_mean_bf16_kernel(
    const uint32_t* __restrict__ tab,
    const int* __restrict__ idxn,
    const int* __restrict__ seg_ids,
    const int* __restrict__ degs,
    float* __restrict__ out,
    int n_out, int E) {
  const int s = blockIdx.x;
  if (s >= n_out) return;
  const int deg = degs[s];
  const int t = threadIdx.x;
  int lo = 0, hi = E;
  while (lo < hi) {
    int mid = (lo + hi) >> 1;
    if (seg_ids[mid] < s) lo = mid + 1; else hi = mid;
  }
  const int start = lo;
  float accx = 0.f, accy = 0.f;
  if (deg > 0) {
    const int dm1 = deg - 1;
    constexpr int U = 16;
    int nidx[U];
#pragma unroll
    for (int k = 0; k < U; ++k) {
      int ei = k < dm1 ? k : dm1;
      nidx[k] = idxn[start + ei];
    }
    for (int e = 0; e < deg; e += U) {
      int cur[U];
#pragma unroll
      for (int k = 0; k < U; ++k) cur[k] = nidx[k];
      const int en = e + U;
      if (en < deg) {
#pragma unroll
        for (int k = 0; k < U; ++k) {
          int ei = en + k;
          ei = ei < dm1 ? ei : dm1;
          nidx[k] = idxn[start + ei];
        }
      }
      uint32_t v[U];
#pragma unroll
      for (int k = 0; k < U; ++k)
        v[k] = tab[(size_t)((uint32_t)cur[k] * 64u + (uint32_t)t)];
      if (en <= deg) {
#pragma unroll
        for (int k = 0; k < U; ++k) {
          accx += __uint_as_float(v[k] << 16);
          accy += __uint_as_float(v[k] & 0xffff0000u);
        }
      } else {
#pragma unroll
        for (int k = 0; k < U; ++k) {
          const float w = (e + k < deg) ? 1.0f : 0.0f;
          accx += __uint_as_float(v[k] << 16) * w;
          accy += __uint_as_float(v[k] & 0xffff0000u) * w;
        }
      }
    }
  }
  const float inv = (deg > 0) ? (1.0f / (float)deg) : 0.0f;
  float2 r;
  r.x = accx * inv;
  r.y = accy * inv;
  ((float2*)out)[(size_t)s * 64 + t] = r;
}

extern "C" void kernel_launch(void* const* d_in, const int* in_sizes, int n_in,
                              void* d_out, int out_size, void* d_ws, size_t ws_size,
                              hipStream_t stream) {
  const float* input  = (const float*)d_in[0];
  const int* idxn     = (const int*)d_in[1];
  const int* seg_ids  = (const int*)d_in[2];
  const int* degs     = (const int*)d_in[3];
  float* out          = (float*)d_out;

  const int n_elem = in_sizes[0];   // N * C
  const int E      = in_sizes[1];
  const int n_out  = in_sizes[3];

  const size_t tab_bytes    = (size_t)n_elem * 2;
  const size_t starts_bytes = (size_t)n_out * 4;

  if (ws_size >= tab_bytes + starts_bytes + 256) {
    uint32_t* tab = (uint32_t*)d_ws;
    size_t starts_off = (tab_bytes + 255) & ~(size_t)255;
    int* starts = (int*)((char*)d_ws + starts_off);

    cvt_bf16_kernel<<<2048, 256, 0, stream>>>(input, tab, n_elem / 4);
    starts_kernel<<<(n_out + 255) / 256, 256, 0, stream>>>(seg_ids, starts,
                                                           n_out, E);
    seg_mean_x4_kernel<<<(n_out + 3) / 4, 256, 0, stream>>>(
        (const uint4*)tab, idxn, starts, degs, out, n_out);
  } else if (ws_size >= tab_bytes) {
    uint32_t* tab = (uint32_t*)d_ws;
    cvt_bf16_kernel<<<2048, 256, 0, stream>>>(input, tab, n_elem / 4);
    seg_mean_bf16_kernel<<<n_out, 64, 0, stream>>>(tab, idxn, seg_ids, degs,
                                                   out, n_out, E);
  }
}